// Round 15
// baseline (224.411 us; speedup 1.0000x reference)
//
#include <hip/hip_runtime.h>
#include <math.h>

#define NIMG 32
#define HWDIM 512
#define NPIX (HWDIM * HWDIM)      // 262144
#define NB 256
#define RAD 4
#define TW 64
#define TH 64

struct W9 { float w[9]; };

__device__ __forceinline__ float clip01(float v) { return fminf(fmaxf(v, 0.0f), 1.0f); }

// ---------------------------------------------------------------------------
// Host-side replica of NumPy's FMA/AVX f32 exp (Pade P5/Q2 + scalef).
// ---------------------------------------------------------------------------
static float np_expf(float x) {
  const float LOG2E = 1.442695040f;
  const float CW_HI = -6.93145752e-1f;
  const float CW_LO = -1.42860677e-6f;
  const float P0 = 9.999999999980870924916e-01f;
  const float P1 = 7.257664613233124478488e-01f;
  const float P2 = 2.473615434895520810817e-01f;
  const float P3 = 5.114512081637298353406e-02f;
  const float P4 = 6.757896990527504603057e-03f;
  const float P5 = 5.082762527590693718096e-04f;
  const float Q0 = 1.000000000000000000000e+00f;
  const float Q1 = -2.742335390411667452936e-01f;
  const float Q2 = 2.159509375685829852307e-02f;
  float m = rintf(x * LOG2E);
  float y = fmaf(m, CW_HI, x);
  y = fmaf(m, CW_LO, y);
  float num = fmaf(fmaf(fmaf(fmaf(fmaf(P5, y, P4), y, P3), y, P2), y, P1), y, P0);
  float den = fmaf(fmaf(Q2, y, Q1), y, Q0);
  float r = num / den;
  return ldexpf(r, (int)m);
}

// ---------------------------------------------------------------------------
// init: min/max, hist, and per-image completion counters (all re-zeroed each
// call -> deterministic across graph replays)
// ---------------------------------------------------------------------------
__global__ __launch_bounds__(256) void init_kernel(int* __restrict__ minI, int* __restrict__ maxI,
                                                   int* __restrict__ hist, int* __restrict__ cnt) {
  int tid = blockIdx.x * blockDim.x + threadIdx.x;
  if (tid < NIMG) { minI[tid] = 0x7F800000; maxI[tid] = 0; cnt[tid] = 0; }
  int stride = gridDim.x * blockDim.x;
  for (int i = tid; i < NIMG * NB; i += stride) hist[i] = 0;
}

// ---------------------------------------------------------------------------
// fused thermal + separable 9-tap blur (vertical then horizontal, edge clamp)
// f64 accumulation per pass, f32 cast (correlate1d semantics — r12 certified).
// Also writes out ch0 = x ch0 for the central tile (fuses mask's passthrough).
// ---------------------------------------------------------------------------
__global__ __launch_bounds__(256) void blur_kernel(const float* __restrict__ x, float* __restrict__ out,
                                                   int* __restrict__ minI, int* __restrict__ maxI, W9 wp) {
  __shared__ float raw[TH + 8][TW + 8];
  __shared__ float vb[TH][TW + 8];
  const int img = blockIdx.z;
  const int tx0 = blockIdx.x * TW;
  const int ty0 = blockIdx.y * TH;
  const float* src = x + (size_t)img * 4 * NPIX;          // channel 0
  float* out0 = out + (size_t)img * 4 * NPIX;             // ch0 passthrough dest
  float* bl = out0 + NPIX;                                 // blurred staged in ch1
  const int tid = threadIdx.x;

  for (int i = tid; i < (TH + 8) * (TW + 8); i += 256) {
    int lr = i / (TW + 8), lc = i % (TW + 8);
    int gr = ty0 - RAD + lr; gr = gr < 0 ? 0 : (gr > HWDIM - 1 ? HWDIM - 1 : gr);
    int gc = tx0 - RAD + lc; gc = gc < 0 ? 0 : (gc > HWDIM - 1 ? HWDIM - 1 : gc);
    float v = src[gr * HWDIM + gc];
    if (lr >= RAD && lr < RAD + TH && lc >= RAD && lc < RAD + TW)
      out0[gr * HWDIM + gc] = v;
    raw[lr][lc] = clip01(__fadd_rn(__fmul_rn(v, 0.5f), 0.5f));
  }
  __syncthreads();

  for (int i = tid; i < TH * (TW + 8); i += 256) {
    int r = i / (TW + 8), c = i % (TW + 8);
    double acc = 0.0;
#pragma unroll
    for (int k = 0; k < 9; ++k) acc += (double)wp.w[k] * (double)raw[r + k][c];
    vb[r][c] = (float)acc;           // f32 cast per pass
  }
  __syncthreads();

  float lmn = __int_as_float(0x7F800000);
  float lmx = 0.0f;
  for (int i = tid; i < TH * TW; i += 256) {
    int r = i >> 6, c = i & 63;
    double acc = 0.0;
#pragma unroll
    for (int k = 0; k < 9; ++k) acc += (double)wp.w[k] * (double)vb[r][c + k];
    float a = (float)acc;
    bl[(ty0 + r) * HWDIM + (tx0 + c)] = a;
    lmn = fminf(lmn, a);
    lmx = fmaxf(lmx, a);
  }
  for (int off = 32; off > 0; off >>= 1) {
    lmn = fminf(lmn, __shfl_down(lmn, off, 64));
    lmx = fmaxf(lmx, __shfl_down(lmx, off, 64));
  }
  __shared__ float smn[4], smx[4];
  if ((tid & 63) == 0) { smn[tid >> 6] = lmn; smx[tid >> 6] = lmx; }
  __syncthreads();
  if (tid == 0) {
    float mnb = fminf(fminf(smn[0], smn[1]), fminf(smn[2], smn[3]));
    float mxb = fmaxf(fmaxf(smx[0], smx[1]), fmaxf(smx[2], smx[3]));
    atomicMin(&minI[img], __float_as_int(mnb));
    atomicMax(&maxI[img], __float_as_int(mxb));
  }
}

// ---------------------------------------------------------------------------
// histogram (16-way LDS sub-hists, pitch 257) + fused Otsu via last-block:
// the final block per image loads the completed global hist (AGENT-scope
// coherent loads) and runs the certified sequential-f32 Otsu on lane 0.
// Binning + Otsu numerics bit-identical to r13.
// ---------------------------------------------------------------------------
__global__ __launch_bounds__(256) void histotsu_kernel(const float* __restrict__ out, const int* __restrict__ minI,
                                                       const int* __restrict__ maxI, int* __restrict__ hist,
                                                       int* __restrict__ cnt, float* __restrict__ t) {
  __shared__ int lh[16 * 257];     // 16448 B
  __shared__ int isLast;
  const int img = blockIdx.y;
  const int tid = threadIdx.x;
  for (int i = tid; i < 16 * 257; i += 256) lh[i] = 0;
  __syncthreads();
  const float mn = __int_as_float(minI[img]);
  const float mx = __int_as_float(maxI[img]);
  const float rng = fmaxf(mx - mn, 1e-12f);
  const float4* src = (const float4*)(out + (size_t)img * 4 * NPIX + NPIX);
  int* my = lh + (tid & 15) * 257;
#pragma unroll
  for (int j = 0; j < 4; ++j) {
    float4 v = src[blockIdx.x * 1024 + j * 256 + tid];
    float q; int b;
    q = __fmul_rn(__fdiv_rn(__fsub_rn(v.x, mn), rng), 256.0f); b = (int)floorf(q); b = b < 0 ? 0 : (b > 255 ? 255 : b); atomicAdd(&my[b], 1);
    q = __fmul_rn(__fdiv_rn(__fsub_rn(v.y, mn), rng), 256.0f); b = (int)floorf(q); b = b < 0 ? 0 : (b > 255 ? 255 : b); atomicAdd(&my[b], 1);
    q = __fmul_rn(__fdiv_rn(__fsub_rn(v.z, mn), rng), 256.0f); b = (int)floorf(q); b = b < 0 ? 0 : (b > 255 ? 255 : b); atomicAdd(&my[b], 1);
    q = __fmul_rn(__fdiv_rn(__fsub_rn(v.w, mn), rng), 256.0f); b = (int)floorf(q); b = b < 0 ? 0 : (b > 255 ? 255 : b); atomicAdd(&my[b], 1);
  }
  __syncthreads();
  int c = 0;
#pragma unroll
  for (int s = 0; s < 16; ++s) c += lh[s * 257 + tid];
  if (c) atomicAdd(&hist[img * NB + tid], c);

  // last-block detection (64 blocks per image)
  if (tid == 0) {
    __threadfence();
    int prev = atomicAdd(&cnt[img], 1);
    isLast = (prev == gridDim.x - 1) ? 1 : 0;
  }
  __syncthreads();
  if (!isLast) return;

  // coherent parallel load of the finished histogram into LDS
  lh[tid] = __hip_atomic_load(&hist[img * NB + tid], __ATOMIC_RELAXED, __HIP_MEMORY_SCOPE_AGENT);
  __syncthreads();
  if (tid != 0) return;

  // certified sequential-f32 Otsu (bit-identical to r13)
  const int* h = lh;
  float* rs = (float*)(lh + 320);    // 257 floats, disjoint from h[0..255]
  const float scale = rng / 256.0f;  // exact
  float acc = 0.0f;
  rs[NB] = 0.0f;
  for (int i = NB - 1; i >= 0; --i) {
    float cc = __fadd_rn(mn, __fmul_rn((float)i + 0.5f, scale));
    acc = __fadd_rn(acc, __fmul_rn((float)h[i], cc));
    rs[i] = acc;
  }
  float w1 = 0.0f, cs1 = 0.0f, best = -INFINITY;
  int arg = 0;
  for (int i = 0; i < NB - 1; ++i) {
    float hi = (float)h[i];
    float cc = __fadd_rn(mn, __fmul_rn((float)i + 0.5f, scale));
    w1 = __fadd_rn(w1, hi);
    cs1 = __fadd_rn(cs1, __fmul_rn(hi, cc));
    float w2n = (float)NPIX - w1;
    float m1 = __fdiv_rn(cs1, fmaxf(w1, 1e-12f));
    float m2n = __fdiv_rn(rs[i + 1], fmaxf(w2n, 1e-12f));
    float d = __fsub_rn(m1, m2n);
    float v = __fmul_rn(__fmul_rn(w1, w2n), __fmul_rn(d, d));
    if (v > best) { best = v; arg = i; }
  }
  t[img] = __fadd_rn(mn, __fmul_rn((float)arg + 0.5f, scale));
}

// ---------------------------------------------------------------------------
// final: ch1..3 = clip(alpha*rgb + (1-alpha)), alpha = bl > t ? 1 : bl.
// ch0 already written by blur. Reads own bl float4 before overwriting.
// ---------------------------------------------------------------------------
__global__ __launch_bounds__(256) void mask_kernel(const float* __restrict__ x, const float* __restrict__ tarr,
                                                   float* __restrict__ out) {
  const int gid = blockIdx.x * 256 + threadIdx.x;
  const int img = gid >> 16;
  const int rem = gid & 65535;
  const float4* xb = (const float4*)(x + (size_t)img * 4 * NPIX);
  float4* ob = (float4*)(out + (size_t)img * 4 * NPIX);
  const float tv = tarr[img];

  float4 bl = ob[65536 + rem];        // blurred staged in ch1 — read before write
  float4 x1 = xb[65536 + rem];
  float4 x2 = xb[2 * 65536 + rem];
  float4 x3 = xb[3 * 65536 + rem];

  float a0 = bl.x > tv ? 1.0f : bl.x;
  float a1 = bl.y > tv ? 1.0f : bl.y;
  float a2 = bl.z > tv ? 1.0f : bl.z;
  float a3 = bl.w > tv ? 1.0f : bl.w;

  float4 o1, o2, o3;
  o1.x = clip01(__fadd_rn(__fmul_rn(a0, x1.x), 1.0f - a0));
  o1.y = clip01(__fadd_rn(__fmul_rn(a1, x1.y), 1.0f - a1));
  o1.z = clip01(__fadd_rn(__fmul_rn(a2, x1.z), 1.0f - a2));
  o1.w = clip01(__fadd_rn(__fmul_rn(a3, x1.w), 1.0f - a3));
  o2.x = clip01(__fadd_rn(__fmul_rn(a0, x2.x), 1.0f - a0));
  o2.y = clip01(__fadd_rn(__fmul_rn(a1, x2.y), 1.0f - a1));
  o2.z = clip01(__fadd_rn(__fmul_rn(a2, x2.z), 1.0f - a2));
  o2.w = clip01(__fadd_rn(__fmul_rn(a3, x2.w), 1.0f - a3));
  o3.x = clip01(__fadd_rn(__fmul_rn(a0, x3.x), 1.0f - a0));
  o3.y = clip01(__fadd_rn(__fmul_rn(a1, x3.y), 1.0f - a1));
  o3.z = clip01(__fadd_rn(__fmul_rn(a2, x3.z), 1.0f - a2));
  o3.w = clip01(__fadd_rn(__fmul_rn(a3, x3.w), 1.0f - a3));

  ob[65536 + rem] = o1;
  ob[2 * 65536 + rem] = o2;
  ob[3 * 65536 + rem] = o3;
}

extern "C" void kernel_launch(void* const* d_in, const int* in_sizes, int n_in,
                              void* d_out, int out_size, void* d_ws, size_t ws_size,
                              hipStream_t stream) {
  const float* x = (const float*)d_in[0];
  float* out = (float*)d_out;
  char* ws = (char*)d_ws;
  int* minI = (int*)(ws + 0);
  int* maxI = (int*)(ws + 128);
  int* hist = (int*)(ws + 256);
  float* t = (float*)(ws + 256 + NIMG * NB * 4);
  int* cnt = (int*)(ws + 256 + NIMG * NB * 4 + NIMG * 4);

  // Gaussian weights: numpy-SIMD f32 exp replica, numpy pairwise 9-sum, f32 div
  W9 wp;
  {
    float k[9];
    for (int i = 0; i < 9; ++i) {
      float xs = (float)(i - 4);
      float argv = -0.5f * (xs * xs);
      k[i] = np_expf(argv);
    }
    float s = ((k[0] + k[1]) + (k[2] + k[3])) + ((k[4] + k[5]) + (k[6] + k[7]));
    s = s + k[8];
    for (int i = 0; i < 9; ++i) wp.w[i] = k[i] / s;
  }

  hipLaunchKernelGGL(init_kernel, dim3(33), dim3(256), 0, stream, minI, maxI, hist, cnt);
  hipLaunchKernelGGL(blur_kernel, dim3(HWDIM / TW, HWDIM / TH, NIMG), dim3(256), 0, stream,
                     x, out, minI, maxI, wp);
  hipLaunchKernelGGL(histotsu_kernel, dim3(NPIX / 16 / 256, NIMG), dim3(256), 0, stream,
                     out, minI, maxI, hist, cnt, t);
  hipLaunchKernelGGL(mask_kernel, dim3(NIMG * NPIX / 4 / 256), dim3(256), 0, stream,
                     x, t, out);
}

// Round 16
// 146.493 us; speedup vs baseline: 1.5319x; 1.5319x over previous
//
#include <hip/hip_runtime.h>
#include <math.h>

#define NIMG 32
#define HWDIM 512
#define NPIX (HWDIM * HWDIM)      // 262144
#define NB 256
#define RAD 4
#define TW 64
#define TH 64

struct W9 { float w[9]; };

__device__ __forceinline__ float clip01(float v) { return fminf(fmaxf(v, 0.0f), 1.0f); }

// ---------------------------------------------------------------------------
// Host-side replica of NumPy's FMA/AVX f32 exp (Pade P5/Q2 + scalef).
// ---------------------------------------------------------------------------
static float np_expf(float x) {
  const float LOG2E = 1.442695040f;
  const float CW_HI = -6.93145752e-1f;
  const float CW_LO = -1.42860677e-6f;
  const float P0 = 9.999999999980870924916e-01f;
  const float P1 = 7.257664613233124478488e-01f;
  const float P2 = 2.473615434895520810817e-01f;
  const float P3 = 5.114512081637298353406e-02f;
  const float P4 = 6.757896990527504603057e-03f;
  const float P5 = 5.082762527590693718096e-04f;
  const float Q0 = 1.000000000000000000000e+00f;
  const float Q1 = -2.742335390411667452936e-01f;
  const float Q2 = 2.159509375685829852307e-02f;
  float m = rintf(x * LOG2E);
  float y = fmaf(m, CW_HI, x);
  y = fmaf(m, CW_LO, y);
  float num = fmaf(fmaf(fmaf(fmaf(fmaf(P5, y, P4), y, P3), y, P2), y, P1), y, P0);
  float den = fmaf(fmaf(Q2, y, Q1), y, Q0);
  float r = num / den;
  return ldexpf(r, (int)m);
}

// ---------------------------------------------------------------------------
// init
// ---------------------------------------------------------------------------
__global__ __launch_bounds__(256) void init_kernel(int* __restrict__ minI, int* __restrict__ maxI,
                                                   int* __restrict__ hist) {
  int tid = blockIdx.x * blockDim.x + threadIdx.x;
  if (tid < NIMG) { minI[tid] = 0x7F800000; maxI[tid] = 0; }
  int stride = gridDim.x * blockDim.x;
  for (int i = tid; i < NIMG * NB; i += stride) hist[i] = 0;
}

// ---------------------------------------------------------------------------
// fused thermal + separable 9-tap blur (vertical then horizontal, edge clamp)
// f64 accumulation per pass, f32 cast (correlate1d semantics — r12 certified).
// Also writes out ch0 = x ch0 for the central tile (fuses mask's passthrough).
// ---------------------------------------------------------------------------
__global__ __launch_bounds__(256) void blur_kernel(const float* __restrict__ x, float* __restrict__ out,
                                                   int* __restrict__ minI, int* __restrict__ maxI, W9 wp) {
  __shared__ float raw[TH + 8][TW + 8];
  __shared__ float vb[TH][TW + 8];
  const int img = blockIdx.z;
  const int tx0 = blockIdx.x * TW;
  const int ty0 = blockIdx.y * TH;
  const float* src = x + (size_t)img * 4 * NPIX;          // channel 0
  float* out0 = out + (size_t)img * 4 * NPIX;             // ch0 passthrough dest
  float* bl = out0 + NPIX;                                 // blurred staged in ch1
  const int tid = threadIdx.x;

  for (int i = tid; i < (TH + 8) * (TW + 8); i += 256) {
    int lr = i / (TW + 8), lc = i % (TW + 8);
    int gr = ty0 - RAD + lr; gr = gr < 0 ? 0 : (gr > HWDIM - 1 ? HWDIM - 1 : gr);
    int gc = tx0 - RAD + lc; gc = gc < 0 ? 0 : (gc > HWDIM - 1 ? HWDIM - 1 : gc);
    float v = src[gr * HWDIM + gc];
    if (lr >= RAD && lr < RAD + TH && lc >= RAD && lc < RAD + TW)
      out0[gr * HWDIM + gc] = v;
    raw[lr][lc] = clip01(__fadd_rn(__fmul_rn(v, 0.5f), 0.5f));
  }
  __syncthreads();

  for (int i = tid; i < TH * (TW + 8); i += 256) {
    int r = i / (TW + 8), c = i % (TW + 8);
    double acc = 0.0;
#pragma unroll
    for (int k = 0; k < 9; ++k) acc += (double)wp.w[k] * (double)raw[r + k][c];
    vb[r][c] = (float)acc;           // f32 cast per pass
  }
  __syncthreads();

  float lmn = __int_as_float(0x7F800000);
  float lmx = 0.0f;
  for (int i = tid; i < TH * TW; i += 256) {
    int r = i >> 6, c = i & 63;
    double acc = 0.0;
#pragma unroll
    for (int k = 0; k < 9; ++k) acc += (double)wp.w[k] * (double)vb[r][c + k];
    float a = (float)acc;
    bl[(ty0 + r) * HWDIM + (tx0 + c)] = a;
    lmn = fminf(lmn, a);
    lmx = fmaxf(lmx, a);
  }
  for (int off = 32; off > 0; off >>= 1) {
    lmn = fminf(lmn, __shfl_down(lmn, off, 64));
    lmx = fmaxf(lmx, __shfl_down(lmx, off, 64));
  }
  __shared__ float smn[4], smx[4];
  if ((tid & 63) == 0) { smn[tid >> 6] = lmn; smx[tid >> 6] = lmx; }
  __syncthreads();
  if (tid == 0) {
    float mnb = fminf(fminf(smn[0], smn[1]), fminf(smn[2], smn[3]));
    float mxb = fmaxf(fmaxf(smx[0], smx[1]), fmaxf(smx[2], smx[3]));
    atomicMin(&minI[img], __float_as_int(mnb));
    atomicMax(&maxI[img], __float_as_int(mxb));
  }
}

// ---------------------------------------------------------------------------
// per-image 256-bin histogram; 16 px/thread, 32-way LDS sub-hists (pitch 257:
// (257*s + b) % 32 spans all 32 banks; same-address collisions 2-way/wave).
// Binning formula bit-identical to r12/r13.
// ---------------------------------------------------------------------------
__global__ __launch_bounds__(256) void hist_kernel(const float* __restrict__ out, const int* __restrict__ minI,
                                                   const int* __restrict__ maxI, int* __restrict__ hist) {
  __shared__ int lh[32 * 257];     // 32896 B
  const int img = blockIdx.y;
  const int tid = threadIdx.x;
  for (int i = tid; i < 32 * 257; i += 256) lh[i] = 0;
  __syncthreads();
  const float mn = __int_as_float(minI[img]);
  const float mx = __int_as_float(maxI[img]);
  const float rng = fmaxf(mx - mn, 1e-12f);
  const float4* src = (const float4*)(out + (size_t)img * 4 * NPIX + NPIX);
  int* my = lh + (tid & 31) * 257;
#pragma unroll
  for (int j = 0; j < 4; ++j) {
    float4 v = src[blockIdx.x * 1024 + j * 256 + tid];
    float q; int b;
    q = __fmul_rn(__fdiv_rn(__fsub_rn(v.x, mn), rng), 256.0f); b = (int)floorf(q); b = b < 0 ? 0 : (b > 255 ? 255 : b); atomicAdd(&my[b], 1);
    q = __fmul_rn(__fdiv_rn(__fsub_rn(v.y, mn), rng), 256.0f); b = (int)floorf(q); b = b < 0 ? 0 : (b > 255 ? 255 : b); atomicAdd(&my[b], 1);
    q = __fmul_rn(__fdiv_rn(__fsub_rn(v.z, mn), rng), 256.0f); b = (int)floorf(q); b = b < 0 ? 0 : (b > 255 ? 255 : b); atomicAdd(&my[b], 1);
    q = __fmul_rn(__fdiv_rn(__fsub_rn(v.w, mn), rng), 256.0f); b = (int)floorf(q); b = b < 0 ? 0 : (b > 255 ? 255 : b); atomicAdd(&my[b], 1);
  }
  __syncthreads();
  int c = 0;
#pragma unroll
  for (int s = 0; s < 32; ++s) c += lh[s * 257 + tid];
  if (c) atomicAdd(&hist[img * NB + tid], c);
}

// ---------------------------------------------------------------------------
// Otsu: 32 blocks (one per image) x 64 threads. Cooperative LDS preload of
// the histogram (kills the 256 serial ~200cy global loads), then lane 0 runs
// the certified sequential-f32 loops from LDS. Numerics bit-identical.
// ---------------------------------------------------------------------------
__global__ __launch_bounds__(64) void otsu_kernel(const int* __restrict__ hist, const int* __restrict__ minI,
                                                  const int* __restrict__ maxI, float* __restrict__ t) {
  __shared__ int h[NB];
  __shared__ float rs[NB + 1];
  const int img = blockIdx.x;
  const int tid = threadIdx.x;
  for (int i = tid; i < NB; i += 64) h[i] = hist[img * NB + i];
  __syncthreads();
  if (tid != 0) return;

  const float mn = __int_as_float(minI[img]);
  const float mx = __int_as_float(maxI[img]);
  const float rng = fmaxf(mx - mn, 1e-12f);
  const float scale = rng / 256.0f;   // exact

  float acc = 0.0f;
  rs[NB] = 0.0f;
  for (int i = NB - 1; i >= 0; --i) {
    float c = __fadd_rn(mn, __fmul_rn((float)i + 0.5f, scale));
    acc = __fadd_rn(acc, __fmul_rn((float)h[i], c));
    rs[i] = acc;
  }

  float w1 = 0.0f, cs1 = 0.0f, best = -INFINITY;
  int arg = 0;
  for (int i = 0; i < NB - 1; ++i) {
    float hi = (float)h[i];
    float c = __fadd_rn(mn, __fmul_rn((float)i + 0.5f, scale));
    w1 = __fadd_rn(w1, hi);
    cs1 = __fadd_rn(cs1, __fmul_rn(hi, c));
    float w2n = (float)NPIX - w1;
    float m1 = __fdiv_rn(cs1, fmaxf(w1, 1e-12f));
    float m2n = __fdiv_rn(rs[i + 1], fmaxf(w2n, 1e-12f));
    float d = __fsub_rn(m1, m2n);
    float v = __fmul_rn(__fmul_rn(w1, w2n), __fmul_rn(d, d));
    if (v > best) { best = v; arg = i; }
  }
  t[img] = __fadd_rn(mn, __fmul_rn((float)arg + 0.5f, scale));
}

// ---------------------------------------------------------------------------
// final: ch1..3 = clip(alpha*rgb + (1-alpha)), alpha = bl > t ? 1 : bl.
// ch0 already written by blur. Reads own bl float4 before overwriting.
// ---------------------------------------------------------------------------
__global__ __launch_bounds__(256) void mask_kernel(const float* __restrict__ x, const float* __restrict__ tarr,
                                                   float* __restrict__ out) {
  const int gid = blockIdx.x * 256 + threadIdx.x;
  const int img = gid >> 16;
  const int rem = gid & 65535;
  const float4* xb = (const float4*)(x + (size_t)img * 4 * NPIX);
  float4* ob = (float4*)(out + (size_t)img * 4 * NPIX);
  const float tv = tarr[img];

  float4 bl = ob[65536 + rem];        // blurred staged in ch1 — read before write
  float4 x1 = xb[65536 + rem];
  float4 x2 = xb[2 * 65536 + rem];
  float4 x3 = xb[3 * 65536 + rem];

  float a0 = bl.x > tv ? 1.0f : bl.x;
  float a1 = bl.y > tv ? 1.0f : bl.y;
  float a2 = bl.z > tv ? 1.0f : bl.z;
  float a3 = bl.w > tv ? 1.0f : bl.w;

  float4 o1, o2, o3;
  o1.x = clip01(__fadd_rn(__fmul_rn(a0, x1.x), 1.0f - a0));
  o1.y = clip01(__fadd_rn(__fmul_rn(a1, x1.y), 1.0f - a1));
  o1.z = clip01(__fadd_rn(__fmul_rn(a2, x1.z), 1.0f - a2));
  o1.w = clip01(__fadd_rn(__fmul_rn(a3, x1.w), 1.0f - a3));
  o2.x = clip01(__fadd_rn(__fmul_rn(a0, x2.x), 1.0f - a0));
  o2.y = clip01(__fadd_rn(__fmul_rn(a1, x2.y), 1.0f - a1));
  o2.z = clip01(__fadd_rn(__fmul_rn(a2, x2.z), 1.0f - a2));
  o2.w = clip01(__fadd_rn(__fmul_rn(a3, x2.w), 1.0f - a3));
  o3.x = clip01(__fadd_rn(__fmul_rn(a0, x3.x), 1.0f - a0));
  o3.y = clip01(__fadd_rn(__fmul_rn(a1, x3.y), 1.0f - a1));
  o3.z = clip01(__fadd_rn(__fmul_rn(a2, x3.z), 1.0f - a2));
  o3.w = clip01(__fadd_rn(__fmul_rn(a3, x3.w), 1.0f - a3));

  ob[65536 + rem] = o1;
  ob[2 * 65536 + rem] = o2;
  ob[3 * 65536 + rem] = o3;
}

extern "C" void kernel_launch(void* const* d_in, const int* in_sizes, int n_in,
                              void* d_out, int out_size, void* d_ws, size_t ws_size,
                              hipStream_t stream) {
  const float* x = (const float*)d_in[0];
  float* out = (float*)d_out;
  char* ws = (char*)d_ws;
  int* minI = (int*)(ws + 0);
  int* maxI = (int*)(ws + 128);
  int* hist = (int*)(ws + 256);
  float* t = (float*)(ws + 256 + NIMG * NB * 4);

  // Gaussian weights: numpy-SIMD f32 exp replica, numpy pairwise 9-sum, f32 div
  W9 wp;
  {
    float k[9];
    for (int i = 0; i < 9; ++i) {
      float xs = (float)(i - 4);
      float argv = -0.5f * (xs * xs);
      k[i] = np_expf(argv);
    }
    float s = ((k[0] + k[1]) + (k[2] + k[3])) + ((k[4] + k[5]) + (k[6] + k[7]));
    s = s + k[8];
    for (int i = 0; i < 9; ++i) wp.w[i] = k[i] / s;
  }

  hipLaunchKernelGGL(init_kernel, dim3(33), dim3(256), 0, stream, minI, maxI, hist);
  hipLaunchKernelGGL(blur_kernel, dim3(HWDIM / TW, HWDIM / TH, NIMG), dim3(256), 0, stream,
                     x, out, minI, maxI, wp);
  hipLaunchKernelGGL(hist_kernel, dim3(NPIX / 16 / 256, NIMG), dim3(256), 0, stream,
                     out, minI, maxI, hist);
  hipLaunchKernelGGL(otsu_kernel, dim3(NIMG), dim3(64), 0, stream, hist, minI, maxI, t);
  hipLaunchKernelGGL(mask_kernel, dim3(NIMG * NPIX / 4 / 256), dim3(256), 0, stream,
                     x, t, out);
}

// Round 17
// 146.441 us; speedup vs baseline: 1.5324x; 1.0004x over previous
//
#include <hip/hip_runtime.h>
#include <math.h>

#define NIMG 32
#define HWDIM 512
#define NPIX (HWDIM * HWDIM)      // 262144
#define NB 256
#define RAD 4
#define TW 64
#define TH 64

struct W9 { float w[9]; };

__device__ __forceinline__ float clip01(float v) { return fminf(fmaxf(v, 0.0f), 1.0f); }

// ---------------------------------------------------------------------------
// Host-side replica of NumPy's FMA/AVX f32 exp (Pade P5/Q2 + scalef).
// ---------------------------------------------------------------------------
static float np_expf(float x) {
  const float LOG2E = 1.442695040f;
  const float CW_HI = -6.93145752e-1f;
  const float CW_LO = -1.42860677e-6f;
  const float P0 = 9.999999999980870924916e-01f;
  const float P1 = 7.257664613233124478488e-01f;
  const float P2 = 2.473615434895520810817e-01f;
  const float P3 = 5.114512081637298353406e-02f;
  const float P4 = 6.757896990527504603057e-03f;
  const float P5 = 5.082762527590693718096e-04f;
  const float Q0 = 1.000000000000000000000e+00f;
  const float Q1 = -2.742335390411667452936e-01f;
  const float Q2 = 2.159509375685829852307e-02f;
  float m = rintf(x * LOG2E);
  float y = fmaf(m, CW_HI, x);
  y = fmaf(m, CW_LO, y);
  float num = fmaf(fmaf(fmaf(fmaf(fmaf(P5, y, P4), y, P3), y, P2), y, P1), y, P0);
  float den = fmaf(fmaf(Q2, y, Q1), y, Q0);
  float r = num / den;
  return ldexpf(r, (int)m);
}

// ---------------------------------------------------------------------------
// init
// ---------------------------------------------------------------------------
__global__ __launch_bounds__(256) void init_kernel(int* __restrict__ minI, int* __restrict__ maxI,
                                                   int* __restrict__ hist) {
  int tid = blockIdx.x * blockDim.x + threadIdx.x;
  if (tid < NIMG) { minI[tid] = 0x7F800000; maxI[tid] = 0; }
  int stride = gridDim.x * blockDim.x;
  for (int i = tid; i < NIMG * NB; i += stride) hist[i] = 0;
}

// ---------------------------------------------------------------------------
// fused thermal + separable 9-tap blur (vertical then horizontal, edge clamp)
// f64 accumulation per pass, f32 cast (correlate1d semantics — r12 certified).
// Also writes out ch0 = x ch0 for the central tile (fuses mask's passthrough).
// ---------------------------------------------------------------------------
__global__ __launch_bounds__(256) void blur_kernel(const float* __restrict__ x, float* __restrict__ out,
                                                   int* __restrict__ minI, int* __restrict__ maxI, W9 wp) {
  __shared__ float raw[TH + 8][TW + 8];
  __shared__ float vb[TH][TW + 8];
  const int img = blockIdx.z;
  const int tx0 = blockIdx.x * TW;
  const int ty0 = blockIdx.y * TH;
  const float* src = x + (size_t)img * 4 * NPIX;          // channel 0
  float* out0 = out + (size_t)img * 4 * NPIX;             // ch0 passthrough dest
  float* bl = out0 + NPIX;                                 // blurred staged in ch1
  const int tid = threadIdx.x;

  for (int i = tid; i < (TH + 8) * (TW + 8); i += 256) {
    int lr = i / (TW + 8), lc = i % (TW + 8);
    int gr = ty0 - RAD + lr; gr = gr < 0 ? 0 : (gr > HWDIM - 1 ? HWDIM - 1 : gr);
    int gc = tx0 - RAD + lc; gc = gc < 0 ? 0 : (gc > HWDIM - 1 ? HWDIM - 1 : gc);
    float v = src[gr * HWDIM + gc];
    if (lr >= RAD && lr < RAD + TH && lc >= RAD && lc < RAD + TW)
      out0[gr * HWDIM + gc] = v;
    raw[lr][lc] = clip01(__fadd_rn(__fmul_rn(v, 0.5f), 0.5f));
  }
  __syncthreads();

  for (int i = tid; i < TH * (TW + 8); i += 256) {
    int r = i / (TW + 8), c = i % (TW + 8);
    double acc = 0.0;
#pragma unroll
    for (int k = 0; k < 9; ++k) acc += (double)wp.w[k] * (double)raw[r + k][c];
    vb[r][c] = (float)acc;           // f32 cast per pass
  }
  __syncthreads();

  float lmn = __int_as_float(0x7F800000);
  float lmx = 0.0f;
  for (int i = tid; i < TH * TW; i += 256) {
    int r = i >> 6, c = i & 63;
    double acc = 0.0;
#pragma unroll
    for (int k = 0; k < 9; ++k) acc += (double)wp.w[k] * (double)vb[r][c + k];
    float a = (float)acc;
    bl[(ty0 + r) * HWDIM + (tx0 + c)] = a;
    lmn = fminf(lmn, a);
    lmx = fmaxf(lmx, a);
  }
  for (int off = 32; off > 0; off >>= 1) {
    lmn = fminf(lmn, __shfl_down(lmn, off, 64));
    lmx = fmaxf(lmx, __shfl_down(lmx, off, 64));
  }
  __shared__ float smn[4], smx[4];
  if ((tid & 63) == 0) { smn[tid >> 6] = lmn; smx[tid >> 6] = lmx; }
  __syncthreads();
  if (tid == 0) {
    float mnb = fminf(fminf(smn[0], smn[1]), fminf(smn[2], smn[3]));
    float mxb = fmaxf(fmaxf(smx[0], smx[1]), fmaxf(smx[2], smx[3]));
    atomicMin(&minI[img], __float_as_int(mnb));
    atomicMax(&maxI[img], __float_as_int(mxb));
  }
}

// ---------------------------------------------------------------------------
// per-image 256-bin histogram; 16 px/thread, 4-way sub-hist (lane&3), pitch
// 260 — byte-identical to r13's kernel (its best-measured config).
// ---------------------------------------------------------------------------
__global__ __launch_bounds__(256) void hist_kernel(const float* __restrict__ out, const int* __restrict__ minI,
                                                   const int* __restrict__ maxI, int* __restrict__ hist) {
  __shared__ int lh[4 * 260];
  const int img = blockIdx.y;
  const int tid = threadIdx.x;
  for (int i = tid; i < 4 * 260; i += 256) lh[i] = 0;
  __syncthreads();
  const float mn = __int_as_float(minI[img]);
  const float mx = __int_as_float(maxI[img]);
  const float rng = fmaxf(mx - mn, 1e-12f);
  const float4* src = (const float4*)(out + (size_t)img * 4 * NPIX + NPIX);
  int* my = lh + (tid & 3) * 260;
#pragma unroll
  for (int j = 0; j < 4; ++j) {
    float4 v = src[blockIdx.x * 1024 + j * 256 + tid];
    float q; int b;
    q = __fmul_rn(__fdiv_rn(__fsub_rn(v.x, mn), rng), 256.0f); b = (int)floorf(q); b = b < 0 ? 0 : (b > 255 ? 255 : b); atomicAdd(&my[b], 1);
    q = __fmul_rn(__fdiv_rn(__fsub_rn(v.y, mn), rng), 256.0f); b = (int)floorf(q); b = b < 0 ? 0 : (b > 255 ? 255 : b); atomicAdd(&my[b], 1);
    q = __fmul_rn(__fdiv_rn(__fsub_rn(v.z, mn), rng), 256.0f); b = (int)floorf(q); b = b < 0 ? 0 : (b > 255 ? 255 : b); atomicAdd(&my[b], 1);
    q = __fmul_rn(__fdiv_rn(__fsub_rn(v.w, mn), rng), 256.0f); b = (int)floorf(q); b = b < 0 ? 0 : (b > 255 ? 255 : b); atomicAdd(&my[b], 1);
  }
  __syncthreads();
  int c = lh[tid] + lh[260 + tid] + lh[2 * 260 + tid] + lh[3 * 260 + tid];
  if (c) atomicAdd(&hist[img * NB + tid], c);
}

// ---------------------------------------------------------------------------
// Otsu: 32 blocks (one per image) x 64 threads. Cooperative LDS preload of
// the histogram (kills ~512 serial ~200cy global loads), then lane 0 runs
// the certified sequential-f32 loops from LDS. Numerics bit-identical.
// ---------------------------------------------------------------------------
__global__ __launch_bounds__(64) void otsu_kernel(const int* __restrict__ hist, const int* __restrict__ minI,
                                                  const int* __restrict__ maxI, float* __restrict__ t) {
  __shared__ int h[NB];
  __shared__ float rs[NB + 1];
  const int img = blockIdx.x;
  const int tid = threadIdx.x;
  for (int i = tid; i < NB; i += 64) h[i] = hist[img * NB + i];
  __syncthreads();
  if (tid != 0) return;

  const float mn = __int_as_float(minI[img]);
  const float mx = __int_as_float(maxI[img]);
  const float rng = fmaxf(mx - mn, 1e-12f);
  const float scale = rng / 256.0f;   // exact

  float acc = 0.0f;
  rs[NB] = 0.0f;
  for (int i = NB - 1; i >= 0; --i) {
    float c = __fadd_rn(mn, __fmul_rn((float)i + 0.5f, scale));
    acc = __fadd_rn(acc, __fmul_rn((float)h[i], c));
    rs[i] = acc;
  }

  float w1 = 0.0f, cs1 = 0.0f, best = -INFINITY;
  int arg = 0;
  for (int i = 0; i < NB - 1; ++i) {
    float hi = (float)h[i];
    float c = __fadd_rn(mn, __fmul_rn((float)i + 0.5f, scale));
    w1 = __fadd_rn(w1, hi);
    cs1 = __fadd_rn(cs1, __fmul_rn(hi, c));
    float w2n = (float)NPIX - w1;
    float m1 = __fdiv_rn(cs1, fmaxf(w1, 1e-12f));
    float m2n = __fdiv_rn(rs[i + 1], fmaxf(w2n, 1e-12f));
    float d = __fsub_rn(m1, m2n);
    float v = __fmul_rn(__fmul_rn(w1, w2n), __fmul_rn(d, d));
    if (v > best) { best = v; arg = i; }
  }
  t[img] = __fadd_rn(mn, __fmul_rn((float)arg + 0.5f, scale));
}

// ---------------------------------------------------------------------------
// final: ch1..3 = clip(alpha*rgb + (1-alpha)), alpha = bl > t ? 1 : bl.
// ch0 already written by blur. Reads own bl float4 before overwriting.
// ---------------------------------------------------------------------------
__global__ __launch_bounds__(256) void mask_kernel(const float* __restrict__ x, const float* __restrict__ tarr,
                                                   float* __restrict__ out) {
  const int gid = blockIdx.x * 256 + threadIdx.x;
  const int img = gid >> 16;
  const int rem = gid & 65535;
  const float4* xb = (const float4*)(x + (size_t)img * 4 * NPIX);
  float4* ob = (float4*)(out + (size_t)img * 4 * NPIX);
  const float tv = tarr[img];

  float4 bl = ob[65536 + rem];        // blurred staged in ch1 — read before write
  float4 x1 = xb[65536 + rem];
  float4 x2 = xb[2 * 65536 + rem];
  float4 x3 = xb[3 * 65536 + rem];

  float a0 = bl.x > tv ? 1.0f : bl.x;
  float a1 = bl.y > tv ? 1.0f : bl.y;
  float a2 = bl.z > tv ? 1.0f : bl.z;
  float a3 = bl.w > tv ? 1.0f : bl.w;

  float4 o1, o2, o3;
  o1.x = clip01(__fadd_rn(__fmul_rn(a0, x1.x), 1.0f - a0));
  o1.y = clip01(__fadd_rn(__fmul_rn(a1, x1.y), 1.0f - a1));
  o1.z = clip01(__fadd_rn(__fmul_rn(a2, x1.z), 1.0f - a2));
  o1.w = clip01(__fadd_rn(__fmul_rn(a3, x1.w), 1.0f - a3));
  o2.x = clip01(__fadd_rn(__fmul_rn(a0, x2.x), 1.0f - a0));
  o2.y = clip01(__fadd_rn(__fmul_rn(a1, x2.y), 1.0f - a1));
  o2.z = clip01(__fadd_rn(__fmul_rn(a2, x2.z), 1.0f - a2));
  o2.w = clip01(__fadd_rn(__fmul_rn(a3, x2.w), 1.0f - a3));
  o3.x = clip01(__fadd_rn(__fmul_rn(a0, x3.x), 1.0f - a0));
  o3.y = clip01(__fadd_rn(__fmul_rn(a1, x3.y), 1.0f - a1));
  o3.z = clip01(__fadd_rn(__fmul_rn(a2, x3.z), 1.0f - a2));
  o3.w = clip01(__fadd_rn(__fmul_rn(a3, x3.w), 1.0f - a3));

  ob[65536 + rem] = o1;
  ob[2 * 65536 + rem] = o2;
  ob[3 * 65536 + rem] = o3;
}

extern "C" void kernel_launch(void* const* d_in, const int* in_sizes, int n_in,
                              void* d_out, int out_size, void* d_ws, size_t ws_size,
                              hipStream_t stream) {
  const float* x = (const float*)d_in[0];
  float* out = (float*)d_out;
  char* ws = (char*)d_ws;
  int* minI = (int*)(ws + 0);
  int* maxI = (int*)(ws + 128);
  int* hist = (int*)(ws + 256);
  float* t = (float*)(ws + 256 + NIMG * NB * 4);

  // Gaussian weights: numpy-SIMD f32 exp replica, numpy pairwise 9-sum, f32 div
  W9 wp;
  {
    float k[9];
    for (int i = 0; i < 9; ++i) {
      float xs = (float)(i - 4);
      float argv = -0.5f * (xs * xs);
      k[i] = np_expf(argv);
    }
    float s = ((k[0] + k[1]) + (k[2] + k[3])) + ((k[4] + k[5]) + (k[6] + k[7]));
    s = s + k[8];
    for (int i = 0; i < 9; ++i) wp.w[i] = k[i] / s;
  }

  hipLaunchKernelGGL(init_kernel, dim3(33), dim3(256), 0, stream, minI, maxI, hist);
  hipLaunchKernelGGL(blur_kernel, dim3(HWDIM / TW, HWDIM / TH, NIMG), dim3(256), 0, stream,
                     x, out, minI, maxI, wp);
  hipLaunchKernelGGL(hist_kernel, dim3(NPIX / 16 / 256, NIMG), dim3(256), 0, stream,
                     out, minI, maxI, hist);
  hipLaunchKernelGGL(otsu_kernel, dim3(NIMG), dim3(64), 0, stream, hist, minI, maxI, t);
  hipLaunchKernelGGL(mask_kernel, dim3(NIMG * NPIX / 4 / 256), dim3(256), 0, stream,
                     x, t, out);
}

// Round 18
// 134.630 us; speedup vs baseline: 1.6669x; 1.0877x over previous
//
#include <hip/hip_runtime.h>
#include <math.h>

#define NIMG 32
#define HWDIM 512
#define NPIX (HWDIM * HWDIM)      // 262144
#define NB 256
#define RAD 4
#define TW 64
#define TH 64

struct W9 { float w[9]; };

__device__ __forceinline__ float clip01(float v) { return fminf(fmaxf(v, 0.0f), 1.0f); }

// ---------------------------------------------------------------------------
// Host-side replica of NumPy's FMA/AVX f32 exp (Pade P5/Q2 + scalef).
// ---------------------------------------------------------------------------
static float np_expf(float x) {
  const float LOG2E = 1.442695040f;
  const float CW_HI = -6.93145752e-1f;
  const float CW_LO = -1.42860677e-6f;
  const float P0 = 9.999999999980870924916e-01f;
  const float P1 = 7.257664613233124478488e-01f;
  const float P2 = 2.473615434895520810817e-01f;
  const float P3 = 5.114512081637298353406e-02f;
  const float P4 = 6.757896990527504603057e-03f;
  const float P5 = 5.082762527590693718096e-04f;
  const float Q0 = 1.000000000000000000000e+00f;
  const float Q1 = -2.742335390411667452936e-01f;
  const float Q2 = 2.159509375685829852307e-02f;
  float m = rintf(x * LOG2E);
  float y = fmaf(m, CW_HI, x);
  y = fmaf(m, CW_LO, y);
  float num = fmaf(fmaf(fmaf(fmaf(fmaf(P5, y, P4), y, P3), y, P2), y, P1), y, P0);
  float den = fmaf(fmaf(Q2, y, Q1), y, Q0);
  float r = num / den;
  return ldexpf(r, (int)m);
}

// ---------------------------------------------------------------------------
// blur: thermal + separable 9-tap (f64 accumulate per pass, f32 cast — r12
// certified), ch0 passthrough fused, per-block min/max -> ws (plain stores).
// ---------------------------------------------------------------------------
__global__ __launch_bounds__(256) void blur_kernel(const float* __restrict__ x, float* __restrict__ out,
                                                   float* __restrict__ mnmx, W9 wp) {
  __shared__ float raw[TH + 8][TW + 8];
  __shared__ float vb[TH][TW + 8];
  const int img = blockIdx.z;
  const int blk = blockIdx.y * 8 + blockIdx.x;            // 0..63 within image
  const int tx0 = blockIdx.x * TW;
  const int ty0 = blockIdx.y * TH;
  const float* src = x + (size_t)img * 4 * NPIX;          // channel 0
  float* out0 = out + (size_t)img * 4 * NPIX;             // ch0 passthrough dest
  float* bl = out0 + NPIX;                                 // blurred staged in ch1
  const int tid = threadIdx.x;

  for (int i = tid; i < (TH + 8) * (TW + 8); i += 256) {
    int lr = i / (TW + 8), lc = i % (TW + 8);
    int gr = ty0 - RAD + lr; gr = gr < 0 ? 0 : (gr > HWDIM - 1 ? HWDIM - 1 : gr);
    int gc = tx0 - RAD + lc; gc = gc < 0 ? 0 : (gc > HWDIM - 1 ? HWDIM - 1 : gc);
    float v = src[gr * HWDIM + gc];
    if (lr >= RAD && lr < RAD + TH && lc >= RAD && lc < RAD + TW)
      out0[gr * HWDIM + gc] = v;
    raw[lr][lc] = clip01(__fadd_rn(__fmul_rn(v, 0.5f), 0.5f));
  }
  __syncthreads();

  for (int i = tid; i < TH * (TW + 8); i += 256) {
    int r = i / (TW + 8), c = i % (TW + 8);
    double acc = 0.0;
#pragma unroll
    for (int k = 0; k < 9; ++k) acc += (double)wp.w[k] * (double)raw[r + k][c];
    vb[r][c] = (float)acc;           // f32 cast per pass
  }
  __syncthreads();

  float lmn = __int_as_float(0x7F800000);
  float lmx = 0.0f;
  for (int i = tid; i < TH * TW; i += 256) {
    int r = i >> 6, c = i & 63;
    double acc = 0.0;
#pragma unroll
    for (int k = 0; k < 9; ++k) acc += (double)wp.w[k] * (double)vb[r][c + k];
    float a = (float)acc;
    bl[(ty0 + r) * HWDIM + (tx0 + c)] = a;
    lmn = fminf(lmn, a);
    lmx = fmaxf(lmx, a);
  }
  for (int off = 32; off > 0; off >>= 1) {
    lmn = fminf(lmn, __shfl_down(lmn, off, 64));
    lmx = fmaxf(lmx, __shfl_down(lmx, off, 64));
  }
  __shared__ float smn[4], smx[4];
  if ((tid & 63) == 0) { smn[tid >> 6] = lmn; smx[tid >> 6] = lmx; }
  __syncthreads();
  if (tid == 0) {
    float mnb = fminf(fminf(smn[0], smn[1]), fminf(smn[2], smn[3]));
    float mxb = fmaxf(fmaxf(smx[0], smx[1]), fmaxf(smx[2], smx[3]));
    mnmx[img * 128 + blk * 2] = mnb;       // plain stores — no init, no atomics
    mnmx[img * 128 + blk * 2 + 1] = mxb;
  }
}

// ---------------------------------------------------------------------------
// hist: prologue reduces the 64 per-block (min,max) pairs (exact, order-free),
// bins 16 px/thread into 4-way LDS sub-hists (pitch 260), writes this block's
// 256-int PARTIAL histogram (plain stores) into the ch2 slot of d_out.
// Binning formula bit-identical to r12..r17.
// ---------------------------------------------------------------------------
__global__ __launch_bounds__(256) void hist_kernel(const float* __restrict__ mnmx, float* __restrict__ out) {
  __shared__ int lh[4 * 260];
  __shared__ float s_mn, s_mx;
  const int img = blockIdx.y;
  const int p = blockIdx.x;            // 0..63
  const int tid = threadIdx.x;
  for (int i = tid; i < 4 * 260; i += 256) lh[i] = 0;

  float lmn = __int_as_float(0x7F800000);
  float lmx = 0.0f;
  if (tid < 64) {
    lmn = mnmx[img * 128 + tid * 2];
    lmx = mnmx[img * 128 + tid * 2 + 1];
  }
  if (tid < 64) {
    for (int off = 32; off > 0; off >>= 1) {
      lmn = fminf(lmn, __shfl_down(lmn, off, 64));
      lmx = fmaxf(lmx, __shfl_down(lmx, off, 64));
    }
    if (tid == 0) { s_mn = lmn; s_mx = lmx; }
  }
  __syncthreads();
  const float mn = s_mn;
  const float mx = s_mx;
  const float rng = fmaxf(mx - mn, 1e-12f);

  const float4* src = (const float4*)(out + (size_t)img * 4 * NPIX + NPIX);
  int* my = lh + (tid & 3) * 260;
#pragma unroll
  for (int j = 0; j < 4; ++j) {
    float4 v = src[p * 1024 + j * 256 + tid];
    float q; int b;
    q = __fmul_rn(__fdiv_rn(__fsub_rn(v.x, mn), rng), 256.0f); b = (int)floorf(q); b = b < 0 ? 0 : (b > 255 ? 255 : b); atomicAdd(&my[b], 1);
    q = __fmul_rn(__fdiv_rn(__fsub_rn(v.y, mn), rng), 256.0f); b = (int)floorf(q); b = b < 0 ? 0 : (b > 255 ? 255 : b); atomicAdd(&my[b], 1);
    q = __fmul_rn(__fdiv_rn(__fsub_rn(v.z, mn), rng), 256.0f); b = (int)floorf(q); b = b < 0 ? 0 : (b > 255 ? 255 : b); atomicAdd(&my[b], 1);
    q = __fmul_rn(__fdiv_rn(__fsub_rn(v.w, mn), rng), 256.0f); b = (int)floorf(q); b = b < 0 ? 0 : (b > 255 ? 255 : b); atomicAdd(&my[b], 1);
  }
  __syncthreads();
  int c = lh[tid] + lh[260 + tid] + lh[2 * 260 + tid] + lh[3 * 260 + tid];
  int* part = (int*)(out + (size_t)img * 4 * NPIX + 2 * NPIX);   // ch2 staging
  part[p * NB + tid] = c;              // plain store — no init, no atomics
}

// ---------------------------------------------------------------------------
// otsu: 32 blocks x 256 threads. Sum the 64 integer partials per bin (exact),
// reduce min/max pairs, then lane 0 runs the certified sequential-f32 loops
// from LDS. Numerics bit-identical to r12..r17.
// ---------------------------------------------------------------------------
__global__ __launch_bounds__(256) void otsu_kernel(const float* __restrict__ mnmx, const float* __restrict__ out,
                                                   float* __restrict__ t) {
  __shared__ int h[NB];
  __shared__ float rs[NB + 1];
  __shared__ float s_mn, s_mx;
  const int img = blockIdx.x;
  const int tid = threadIdx.x;
  const int* part = (const int*)(out + (size_t)img * 4 * NPIX + 2 * NPIX);
  int sum = 0;
#pragma unroll 8
  for (int p = 0; p < 64; ++p) sum += part[p * NB + tid];
  h[tid] = sum;

  float lmn = __int_as_float(0x7F800000);
  float lmx = 0.0f;
  if (tid < 64) {
    lmn = mnmx[img * 128 + tid * 2];
    lmx = mnmx[img * 128 + tid * 2 + 1];
    for (int off = 32; off > 0; off >>= 1) {
      lmn = fminf(lmn, __shfl_down(lmn, off, 64));
      lmx = fmaxf(lmx, __shfl_down(lmx, off, 64));
    }
    if (tid == 0) { s_mn = lmn; s_mx = lmx; }
  }
  __syncthreads();
  if (tid != 0) return;

  const float mn = s_mn;
  const float mx = s_mx;
  const float rng = fmaxf(mx - mn, 1e-12f);
  const float scale = rng / 256.0f;   // exact

  float acc = 0.0f;
  rs[NB] = 0.0f;
  for (int i = NB - 1; i >= 0; --i) {
    float c = __fadd_rn(mn, __fmul_rn((float)i + 0.5f, scale));
    acc = __fadd_rn(acc, __fmul_rn((float)h[i], c));
    rs[i] = acc;
  }

  float w1 = 0.0f, cs1 = 0.0f, best = -INFINITY;
  int arg = 0;
  for (int i = 0; i < NB - 1; ++i) {
    float hi = (float)h[i];
    float c = __fadd_rn(mn, __fmul_rn((float)i + 0.5f, scale));
    w1 = __fadd_rn(w1, hi);
    cs1 = __fadd_rn(cs1, __fmul_rn(hi, c));
    float w2n = (float)NPIX - w1;
    float m1 = __fdiv_rn(cs1, fmaxf(w1, 1e-12f));
    float m2n = __fdiv_rn(rs[i + 1], fmaxf(w2n, 1e-12f));
    float d = __fsub_rn(m1, m2n);
    float v = __fmul_rn(__fmul_rn(w1, w2n), __fmul_rn(d, d));
    if (v > best) { best = v; arg = i; }
  }
  t[img] = __fadd_rn(mn, __fmul_rn((float)arg + 0.5f, scale));
}

// ---------------------------------------------------------------------------
// mask: ch1..3 = clip(alpha*rgb + (1-alpha)), alpha = bl > t ? 1 : bl.
// ch0 written by blur; partial-hist staging in ch2 is overwritten here (after
// otsu consumed it — stream ordering guarantees). Reads own bl before write.
// ---------------------------------------------------------------------------
__global__ __launch_bounds__(256) void mask_kernel(const float* __restrict__ x, const float* __restrict__ tarr,
                                                   float* __restrict__ out) {
  const int gid = blockIdx.x * 256 + threadIdx.x;
  const int img = gid >> 16;
  const int rem = gid & 65535;
  const float4* xb = (const float4*)(x + (size_t)img * 4 * NPIX);
  float4* ob = (float4*)(out + (size_t)img * 4 * NPIX);
  const float tv = tarr[img];

  float4 bl = ob[65536 + rem];        // blurred staged in ch1 — read before write
  float4 x1 = xb[65536 + rem];
  float4 x2 = xb[2 * 65536 + rem];
  float4 x3 = xb[3 * 65536 + rem];

  float a0 = bl.x > tv ? 1.0f : bl.x;
  float a1 = bl.y > tv ? 1.0f : bl.y;
  float a2 = bl.z > tv ? 1.0f : bl.z;
  float a3 = bl.w > tv ? 1.0f : bl.w;

  float4 o1, o2, o3;
  o1.x = clip01(__fadd_rn(__fmul_rn(a0, x1.x), 1.0f - a0));
  o1.y = clip01(__fadd_rn(__fmul_rn(a1, x1.y), 1.0f - a1));
  o1.z = clip01(__fadd_rn(__fmul_rn(a2, x1.z), 1.0f - a2));
  o1.w = clip01(__fadd_rn(__fmul_rn(a3, x1.w), 1.0f - a3));
  o2.x = clip01(__fadd_rn(__fmul_rn(a0, x2.x), 1.0f - a0));
  o2.y = clip01(__fadd_rn(__fmul_rn(a1, x2.y), 1.0f - a1));
  o2.z = clip01(__fadd_rn(__fmul_rn(a2, x2.z), 1.0f - a2));
  o2.w = clip01(__fadd_rn(__fmul_rn(a3, x2.w), 1.0f - a3));
  o3.x = clip01(__fadd_rn(__fmul_rn(a0, x3.x), 1.0f - a0));
  o3.y = clip01(__fadd_rn(__fmul_rn(a1, x3.y), 1.0f - a1));
  o3.z = clip01(__fadd_rn(__fmul_rn(a2, x3.z), 1.0f - a2));
  o3.w = clip01(__fadd_rn(__fmul_rn(a3, x3.w), 1.0f - a3));

  ob[65536 + rem] = o1;
  ob[2 * 65536 + rem] = o2;
  ob[3 * 65536 + rem] = o3;
}

extern "C" void kernel_launch(void* const* d_in, const int* in_sizes, int n_in,
                              void* d_out, int out_size, void* d_ws, size_t ws_size,
                              hipStream_t stream) {
  const float* x = (const float*)d_in[0];
  float* out = (float*)d_out;
  char* ws = (char*)d_ws;
  float* mnmx = (float*)(ws + 0);                 // 32*64*2 floats = 16 KB
  float* t = (float*)(ws + 32 * 128 * 4);         // 32 floats

  // Gaussian weights: numpy-SIMD f32 exp replica, numpy pairwise 9-sum, f32 div
  W9 wp;
  {
    float k[9];
    for (int i = 0; i < 9; ++i) {
      float xs = (float)(i - 4);
      float argv = -0.5f * (xs * xs);
      k[i] = np_expf(argv);
    }
    float s = ((k[0] + k[1]) + (k[2] + k[3])) + ((k[4] + k[5]) + (k[6] + k[7]));
    s = s + k[8];
    for (int i = 0; i < 9; ++i) wp.w[i] = k[i] / s;
  }

  hipLaunchKernelGGL(blur_kernel, dim3(HWDIM / TW, HWDIM / TH, NIMG), dim3(256), 0, stream,
                     x, out, mnmx, wp);
  hipLaunchKernelGGL(hist_kernel, dim3(64, NIMG), dim3(256), 0, stream, mnmx, out);
  hipLaunchKernelGGL(otsu_kernel, dim3(NIMG), dim3(256), 0, stream, mnmx, out, t);
  hipLaunchKernelGGL(mask_kernel, dim3(NIMG * NPIX / 4 / 256), dim3(256), 0, stream,
                     x, t, out);
}